// Round 3
// baseline (294.045 us; speedup 1.0000x reference)
//
#include <hip/hip_runtime.h>

// ConvNat: 2x NAT(31x31, 4 heads, dh=16) on 36x36x64 + dw-conv3x3 residual + linear.
// fp32. R2: split-K attention (4 blocks/tile) for occupancy; combine kernel does
// normalize+projection; layer-2 combine also fuses dwconv residual + final linear.

namespace {

__device__ __forceinline__ int iclampi(int v, int lo, int hi) {
  return v < lo ? lo : (v > hi ? hi : v);
}

// out[n][t] = b[t] + sum_c x[n][c] * w[t][c]
// grid = 972 (4 pixels x 64-out chunk per block), block = 256
__global__ __launch_bounds__(256) void qkv_gemm(const float* __restrict__ xin,
                                                const float* __restrict__ w,
                                                const float* __restrict__ b,
                                                float* __restrict__ out) {
  __shared__ float xs[4][64];
  const int blk = blockIdx.x;
  const int oc = blk % 3;        // which 64-wide output chunk of 192
  const int p0 = (blk / 3) * 4;  // first pixel of 4
  const int tid = threadIdx.x;
  const int pl = tid >> 6, co = tid & 63;
  const int n = p0 + pl;
  xs[pl][co] = xin[n * 64 + co];
  __syncthreads();
  const int t = oc * 64 + co;
  const float4* w4 = (const float4*)(w + t * 64);
  float acc = b[t];
#pragma unroll
  for (int u = 0; u < 16; ++u) {
    float4 wv = w4[u];
    acc += xs[pl][u * 4 + 0] * wv.x + xs[pl][u * 4 + 1] * wv.y +
           xs[pl][u * 4 + 2] * wv.z + xs[pl][u * 4 + 3] * wv.w;
  }
  out[n * 192 + t] = acc;
}

// Split-K neighborhood attention partials.
// grid = 324 tiles * 4 splits, block = 256 (wave = head).
// Split s covers key rows [s*8, s*8+8) of the tile's <=32-row window union:
// 4 iterations of 2 rows x 32 cols per wave. Output: per (tile,split,head)
// 68 floats: [q*17 + d] acc (q<4,d<16), [q*17+16] = denominator.
__global__ __launch_bounds__(256, 4) void nat_attn_part(
    const float* __restrict__ qkv, const float* __restrict__ rpb,
    float* __restrict__ part) {
  __shared__ float lpart[4][16][69];  // [head][group][4q*17] padded stride 69

  const int tid = threadIdx.x;
  const int h = tid >> 6;
  const int lane = tid & 63;
  const int bid = blockIdx.x;
  const int tile = bid >> 2;
  const int s = bid & 3;
  const int i0 = (tile / 18) * 2;
  const int j0 = (tile % 18) * 2;

  const int r_lo = iclampi(i0 - 15, 0, 5);
  const int r_hi = iclampi(i0 - 14, 0, 5) + 30;
  const int c_lo = iclampi(j0 - 15, 0, 5);
  const int nRr = r_hi - r_lo;  // 30 or 31
  const int nCc = (iclampi(j0 - 14, 0, 5) + 30) - c_lo;

  int iq[4], jq[4], riq[4], cjq[4];
#pragma unroll
  for (int qq = 0; qq < 4; ++qq) {
    iq[qq] = i0 + (qq >> 1);
    jq[qq] = j0 + (qq & 1);
    riq[qq] = iclampi(iq[qq] - 15, 0, 5);
    cjq[qq] = iclampi(jq[qq] - 15, 0, 5);
  }

  // queries, pre-scaled by dh^-0.5 = 0.25 (broadcast loads: same addr all lanes)
  float qv[4][16];
#pragma unroll
  for (int qq = 0; qq < 4; ++qq) {
    const float4* qp = (const float4*)(qkv + (iq[qq] * 36 + jq[qq]) * 192 + h * 16);
#pragma unroll
    for (int u = 0; u < 4; ++u) {
      float4 q4 = qp[u];
      qv[qq][u * 4 + 0] = q4.x * 0.25f;
      qv[qq][u * 4 + 1] = q4.y * 0.25f;
      qv[qq][u * 4 + 2] = q4.z * 0.25f;
      qv[qq][u * 4 + 3] = q4.w * 0.25f;
    }
  }

  float acc[4][16];
  float sden[4] = {0.f, 0.f, 0.f, 0.f};
#pragma unroll
  for (int qq = 0; qq < 4; ++qq)
#pragma unroll
    for (int d = 0; d < 16; ++d) acc[qq][d] = 0.f;

  const int lr = lane >> 5;
  const int lc = lane & 31;

#pragma unroll
  for (int rp = 0; rp < 4; ++rp) {
    const int krr = s * 8 + rp * 2 + lr;
    const int rA = r_lo + krr;
    const int cA = c_lo + lc;
    const bool act = (krr <= nRr) && (lc <= nCc);
    const int rL = rA > 35 ? 35 : rA;
    const int cL = cA > 35 ? 35 : cA;
    const float* kbase = qkv + (rL * 36 + cL) * 192 + 64 + h * 16;
    float kr_[16], vr_[16];
#pragma unroll
    for (int u = 0; u < 4; ++u) {
      float4 k4 = ((const float4*)kbase)[u];
      kr_[u * 4 + 0] = k4.x; kr_[u * 4 + 1] = k4.y;
      kr_[u * 4 + 2] = k4.z; kr_[u * 4 + 3] = k4.w;
      float4 v4 = ((const float4*)(kbase + 64))[u];
      vr_[u * 4 + 0] = v4.x; vr_[u * 4 + 1] = v4.y;
      vr_[u * 4 + 2] = v4.z; vr_[u * 4 + 3] = v4.w;
    }
#pragma unroll
    for (int qq = 0; qq < 4; ++qq) {
      float dot = 0.f;
#pragma unroll
      for (int d = 0; d < 16; ++d) dot += qv[qq][d] * kr_[d];
      const bool inw = act && (rA >= riq[qq]) && (rA <= riq[qq] + 30) &&
                       (cA >= cjq[qq]) && (cA <= cjq[qq] + 30);
      const int br = iclampi(rA - iq[qq] + 30, 0, 60);
      const int bc = iclampi(cA - jq[qq] + 30, 0, 60);
      const float bias = rpb[h * 3721 + br * 61 + bc];
      // |logits| << 1 for this input distribution; clamp = overflow insurance
      const float lg = fminf(dot + bias, 25.f);
      const float p = inw ? __expf(lg) : 0.f;
      sden[qq] += p;
#pragma unroll
      for (int d = 0; d < 16; ++d) acc[qq][d] += p * vr_[d];
    }
  }

  // 2-step butterfly -> 16 groups of 4 lanes
#pragma unroll
  for (int qq = 0; qq < 4; ++qq) {
#pragma unroll
    for (int d = 0; d < 16; ++d) {
      acc[qq][d] += __shfl_xor(acc[qq][d], 1);
      acc[qq][d] += __shfl_xor(acc[qq][d], 2);
    }
    sden[qq] += __shfl_xor(sden[qq], 1);
    sden[qq] += __shfl_xor(sden[qq], 2);
  }

  if ((lane & 3) == 0) {
    const int row = lane >> 2;
#pragma unroll
    for (int qq = 0; qq < 4; ++qq) {
#pragma unroll
      for (int d = 0; d < 16; ++d) lpart[h][row][qq * 17 + d] = acc[qq][d];
      lpart[h][row][qq * 17 + 16] = sden[qq];
    }
  }
  // wave-private LDS (per-head slab): no __syncthreads needed.

  float* wsout = part + (size_t)(bid * 4 + h) * 72;
  {
    float t0 = 0.f;
#pragma unroll
    for (int l = 0; l < 16; ++l) t0 += lpart[h][l][lane];
    wsout[lane] = t0;
    if (lane < 4) {
      float t1 = 0.f;
#pragma unroll
      for (int l = 0; l < 16; ++l) t1 += lpart[h][l][lane + 64];
      wsout[lane + 64] = t1;
    }
  }
}

// Combine partials -> softmax-normalize -> projection.
// FINAL adds dwconv(x) residual + final linear. grid=324, block=256 (wave=query).
template <bool FINAL>
__global__ __launch_bounds__(256) void nat_combine(
    const float* __restrict__ part, const float* __restrict__ pw,
    const float* __restrict__ pb, const float* __restrict__ x,
    const float* __restrict__ dww, const float* __restrict__ dwb,
    const float* __restrict__ lw, const float* __restrict__ lb,
    float* __restrict__ out) {
  __shared__ float att[4][64];
  __shared__ float y_lds[4][64];
  const int tid = threadIdx.x;
  const int q = tid >> 6, lane = tid & 63;
  const int tile = blockIdx.x;
  const int i0 = (tile / 18) * 2, j0 = (tile % 18) * 2;
  const int iq = i0 + (q >> 1), jq = j0 + (q & 1);
  const int n = iq * 36 + jq;

  const int hh = lane >> 4, dd = lane & 15;
  const float* pbase = part + (size_t)tile * 1152 + hh * 72;
  float num = 0.f, den = 0.f;
#pragma unroll
  for (int sp = 0; sp < 4; ++sp) {
    num += pbase[sp * 288 + q * 17 + dd];
    den += pbase[sp * 288 + q * 17 + 16];
  }
  att[q][lane] = num / den;
  __syncthreads();

  const float4* w4 = (const float4*)(pw + lane * 64);
  float a = pb[lane];
#pragma unroll
  for (int u = 0; u < 16; ++u) {
    float4 wv = w4[u];
    a += att[q][u * 4 + 0] * wv.x + att[q][u * 4 + 1] * wv.y +
         att[q][u * 4 + 2] * wv.z + att[q][u * 4 + 3] * wv.w;
  }

  if (!FINAL) {
    out[n * 64 + lane] = a;
  } else {
    float y = a + dwb[lane];
#pragma unroll
    for (int di = -1; di <= 1; ++di) {
#pragma unroll
      for (int dj = -1; dj <= 1; ++dj) {
        const int ii = iq + di, jj = jq + dj;
        if (ii >= 0 && ii < 36 && jj >= 0 && jj < 36)
          y += x[(ii * 36 + jj) * 64 + lane] * dww[lane * 9 + (di + 1) * 3 + (dj + 1)];
      }
    }
    y_lds[q][lane] = y;
    __syncthreads();
    const float4* l4 = (const float4*)(lw + lane * 64);
    float o = lb[lane];
#pragma unroll
    for (int u = 0; u < 16; ++u) {
      float4 wv = l4[u];
      o += y_lds[q][u * 4 + 0] * wv.x + y_lds[q][u * 4 + 1] * wv.y +
           y_lds[q][u * 4 + 2] * wv.z + y_lds[q][u * 4 + 3] * wv.w;
    }
    out[n * 64 + lane] = o;
  }
}

}  // namespace

extern "C" void kernel_launch(void* const* d_in, const int* in_sizes, int n_in,
                              void* d_out, int out_size, void* d_ws, size_t ws_size,
                              hipStream_t stream) {
  const float* x       = (const float*)d_in[0];
  const float* qkv_w1  = (const float*)d_in[3];
  const float* qkv_b1  = (const float*)d_in[4];
  const float* rpb1    = (const float*)d_in[5];
  const float* proj_w1 = (const float*)d_in[6];
  const float* proj_b1 = (const float*)d_in[7];
  const float* qkv_w2  = (const float*)d_in[8];
  const float* qkv_b2  = (const float*)d_in[9];
  const float* rpb2    = (const float*)d_in[10];
  const float* proj_w2 = (const float*)d_in[11];
  const float* proj_b2 = (const float*)d_in[12];
  const float* dw_w    = (const float*)d_in[13];
  const float* dw_b    = (const float*)d_in[14];
  const float* lin_w   = (const float*)d_in[15];
  const float* lin_b   = (const float*)d_in[16];
  float* out = (float*)d_out;

  float* ws = (float*)d_ws;
  float* qkvb  = ws;             // 1296*192 = 248832 floats
  float* natA  = ws + 248832;    // 1296*64  =  82944 floats
  float* partb = natA + 82944;   // 1296*4*72 = 373248 floats

  // layer 1
  qkv_gemm<<<972, 256, 0, stream>>>(x, qkv_w1, qkv_b1, qkvb);
  nat_attn_part<<<1296, 256, 0, stream>>>(qkvb, rpb1, partb);
  nat_combine<false><<<324, 256, 0, stream>>>(partb, proj_w1, proj_b1, nullptr,
                                              nullptr, nullptr, nullptr, nullptr,
                                              natA);
  // layer 2
  qkv_gemm<<<972, 256, 0, stream>>>(natA, qkv_w2, qkv_b2, qkvb);
  nat_attn_part<<<1296, 256, 0, stream>>>(qkvb, rpb2, partb);
  // layer-2 combine fused with dwconv residual + final linear
  nat_combine<true><<<324, 256, 0, stream>>>(partb, proj_w2, proj_b2, x,
                                             dw_w, dw_b, lin_w, lin_b, out);
}